// Round 12
// baseline (111.830 us; speedup 1.0000x reference)
//
#include <hip/hip_runtime.h>
#include <hip/hip_bf16.h>

typedef __attribute__((ext_vector_type(8))) short bf16x8s;   // 8 bf16 as shorts (MFMA frag)
typedef __attribute__((ext_vector_type(4))) float f32x4;
typedef __attribute__((ext_vector_type(16))) float f32x16;
typedef __attribute__((ext_vector_type(4))) __bf16 bf16x4;
typedef __attribute__((ext_vector_type(8))) __bf16 bf16x8;

typedef const __attribute__((address_space(1))) void gvoid_t;
typedef __attribute__((address_space(3))) void lvoid_t;

constexpr int Bc = 2, Tc = 2048, Dc = 1024, Hc = 16, HDc = 64;
constexpr int Mc = Bc * Tc;  // 4096

// ---------------- fused fp32 -> bf16 convert: x (4096 blocks) + 4 weights (4096) ----
__global__ void cvt_all(const float* __restrict__ x,
                        const float* __restrict__ wq, const float* __restrict__ wk,
                        const float* __restrict__ wv, const float* __restrict__ wp,
                        __bf16* __restrict__ xb, __bf16* __restrict__ wb) {
  const int bid = blockIdx.x;
  const float* src;
  __bf16* dst;
  int i;
  if (bid < 4096) {
    src = x; dst = xb; i = (bid * 256 + threadIdx.x) * 4;
  } else {
    const int r = bid - 4096;
    const int w = r >> 10;
    src = (w == 0) ? wq : (w == 1) ? wk : (w == 2) ? wv : wp;
    dst = wb + (size_t)w * (Dc * Dc);
    i = ((r & 1023) * 256 + threadIdx.x) * 4;
  }
  float4 v = *(const float4*)(src + i);
  bf16x4 o;
  o[0] = (__bf16)v.x; o[1] = (__bf16)v.y; o[2] = (__bf16)v.z; o[3] = (__bf16)v.w;
  *(bf16x4*)(dst + i) = o;
}

// ---------------- QKV GEMM (v2): 128x64 tiles, one head per block -----------------
// C[m][e] = sum_d A[m][d] * W[e][d]. 4 waves x (32 rows x 64 cols), acc[2][4].
// grid (16, 32, 3) = 1536 blocks -> 6 blocks/CU (24KB LDS). z=0: RoPE+scale;
// z=1: RoPE; z=2: V^T single-pass LDS bounce -> vt [B,H,HD,T].
// RoPE uses cos[t,i+32]==cos[t,i] (emb = concat(freqs,freqs)) -> half the loads.
__launch_bounds__(256, 4)
__global__ void gemm_qkv(const __bf16* __restrict__ A,
                         const __bf16* __restrict__ W,
                         __bf16* __restrict__ outb,
                         __bf16* __restrict__ vtout,
                         const float* __restrict__ cbt,
                         const float* __restrict__ sbt) {
  __shared__ __bf16 smem[12288];        // A 128x64 (16KB) + B 64x64 (8KB)
  __bf16* Alds = smem;
  __bf16* Blds = smem + 8192;
  const int tid = threadIdx.x;
  const int lane = tid & 63, wid = tid >> 6;
  const int lr = lane & 15, lg = lane >> 4;
  // XCD-chunked remap: each XCD owns 4 M-rows x 16 N-cols (1MB A + 2MB W in L2)
  const int lid = blockIdx.x + (int)gridDim.x * blockIdx.y;   // [0,512)
  const int xcd = lid & 7, g = lid >> 3;                      // g in [0,64)
  const int brow = (xcd * 4 + (g & 3)) * 128;
  const int bcol = (g >> 2) * 64;
  const __bf16* Wm = W + (size_t)blockIdx.z * (Dc * Dc);

  f32x4 acc[2][4] = {};

  const char* Ag = (const char*)(A + (size_t)brow * Dc);
  const char* Bg = (const char*)(Wm + (size_t)bcol * Dc);
  const int r0 = tid >> 3;
  const int cb = (tid & 7) * 16;

  for (int k0 = 0; k0 < Dc; k0 += 64) {
#pragma unroll
    for (int i = 0; i < 4; ++i) {
      const int r = i * 32 + r0;
      const int ldsoff = (i * 256 + wid * 64) * 16;
      __builtin_amdgcn_global_load_lds(
          (gvoid_t*)(Ag + (size_t)r * (Dc * 2) + k0 * 2 + cb),
          (lvoid_t*)((char*)Alds + ldsoff), 16, 0, 0);
    }
#pragma unroll
    for (int i = 0; i < 2; ++i) {
      const int r = i * 32 + r0;
      const int ldsoff = (i * 256 + wid * 64) * 16;
      __builtin_amdgcn_global_load_lds(
          (gvoid_t*)(Bg + (size_t)r * (Dc * 2) + k0 * 2 + cb),
          (lvoid_t*)((char*)Blds + ldsoff), 16, 0, 0);
    }
    __syncthreads();
#pragma unroll
    for (int kk = 0; kk < 2; ++kk) {
      const int col = kk * 32 + lg * 8;
      bf16x8s af[2], bfv[4];
#pragma unroll
      for (int m = 0; m < 2; ++m)
        af[m] = *(const bf16x8s*)(Alds + (wid * 32 + m * 16 + lr) * 64 + col);
#pragma unroll
      for (int n = 0; n < 4; ++n)
        bfv[n] = *(const bf16x8s*)(Blds + (n * 16 + lr) * 64 + col);
#pragma unroll
      for (int m = 0; m < 2; ++m)
#pragma unroll
        for (int n = 0; n < 4; ++n)
          acc[m][n] = __builtin_amdgcn_mfma_f32_16x16x32_bf16(af[m], bfv[n], acc[m][n], 0, 0, 0);
    }
    __syncthreads();
  }

  const int z = blockIdx.z;
  if (z == 2) {
    // V^T epilogue: C^T via LDS [64 hd][136], coalesced 16B stores to vt
    const int bb = brow >> 11, t0b = brow & (Tc - 1);
    const int h = bcol >> 6;
    __bf16* tile_t = smem;  // [64][136]
#pragma unroll
    for (int m = 0; m < 2; ++m)
#pragma unroll
      for (int n = 0; n < 4; ++n) {
        bf16x4 pb;
#pragma unroll
        for (int j = 0; j < 4; ++j) pb[j] = (__bf16)acc[m][n][j];
        *(bf16x4*)(tile_t + (n * 16 + lr) * 136 + wid * 32 + m * 16 + lg * 4) = pb;
      }
    __syncthreads();
    __bf16* vdst = vtout + (((size_t)bb * Hc + h) * HDc) * Tc + t0b;
#pragma unroll
    for (int p = 0; p < 4; ++p) {
      const int r = p * 16 + (tid >> 4);
      const int c8 = (tid & 15) * 8;
      bf16x8 vvv = *(const bf16x8*)(tile_t + r * 136 + c8);
      *(bf16x8*)(vdst + (size_t)r * Tc + c8) = vvv;
    }
    return;
  }

  // z==0/1: fused RoPE (+ score scale for Q), scatter to [B,H,T,HD]
  {
    const float scl = (z == 0) ? 0.18033688011112042f : 1.0f;  // (1/8)*log2(e)
    const int h = bcol >> 6;
#pragma unroll
    for (int m = 0; m < 2; ++m) {
#pragma unroll
      for (int j = 0; j < 4; ++j) {
        const int gm = brow + wid * 32 + m * 16 + lg * 4 + j;
        const float* cbase = cbt + (size_t)gm * HDc;
        const float* sbase = sbt + (size_t)gm * HDc;
#pragma unroll
        for (int n = 0; n < 2; ++n) {
          const int i = n * 16 + lr;
          const float c0 = cbase[i], s0 = sbase[i];   // cos[i+32]==cos[i]
          const float v0 = acc[m][n][j], v1 = acc[m][n + 2][j];
          acc[m][n][j]     = (v0 * c0 - v1 * s0) * scl;
          acc[m][n + 2][j] = (v1 * c0 + v0 * s0) * scl;
        }
      }
    }
    __bf16* dst = outb + (size_t)z * ((size_t)Mc * Dc);
#pragma unroll
    for (int m = 0; m < 2; ++m) {
#pragma unroll
      for (int j = 0; j < 4; ++j) {
        const int gm = brow + wid * 32 + m * 16 + lg * 4 + j;
        const int bb = gm >> 11, t = gm & (Tc - 1);
        __bf16* rowp = dst + (((size_t)bb * Hc + h) * Tc + t) * HDc;
#pragma unroll
        for (int n = 0; n < 4; ++n) rowp[n * 16 + lr] = (__bf16)acc[m][n][j];
      }
    }
  }
}

// ---------------- output projection GEMM (v2): 64x64 tiles, 1024 blocks (4/CU) -----
__launch_bounds__(256, 4)
__global__ void gemm_proj(const __bf16* __restrict__ A, const __bf16* __restrict__ W,
                          float* __restrict__ outf) {
  __shared__ __bf16 smem[8192];         // A 64x64 (8KB) + B 64x64 (8KB)
  __bf16* Alds = smem;
  __bf16* Blds = smem + 4096;
  const int tid = threadIdx.x;
  const int lane = tid & 63, wid = tid >> 6;
  const int lr = lane & 15, lg = lane >> 4;
  const int lid = blockIdx.x;                         // [0,1024)
  const int xcd = lid & 7, g = lid >> 3;              // g in [0,128)
  const int brow = (xcd * 8 + (g & 7)) * 64;
  const int bcol = (g >> 3) * 64;
  f32x4 acc[4] = {};
  const char* Ag = (const char*)(A + (size_t)brow * Dc);
  const char* Bg = (const char*)(W + (size_t)bcol * Dc);
  const int r0 = tid >> 3;
  const int cb = (tid & 7) * 16;
  for (int k0 = 0; k0 < Dc; k0 += 64) {
#pragma unroll
    for (int i = 0; i < 2; ++i) {
      const int r = i * 32 + r0;
      const int ldsoff = (i * 256 + wid * 64) * 16;
      __builtin_amdgcn_global_load_lds(
          (gvoid_t*)(Ag + (size_t)r * (Dc * 2) + k0 * 2 + cb),
          (lvoid_t*)((char*)Alds + ldsoff), 16, 0, 0);
      __builtin_amdgcn_global_load_lds(
          (gvoid_t*)(Bg + (size_t)r * (Dc * 2) + k0 * 2 + cb),
          (lvoid_t*)((char*)Blds + ldsoff), 16, 0, 0);
    }
    __syncthreads();
#pragma unroll
    for (int kk = 0; kk < 2; ++kk) {
      const int col = kk * 32 + lg * 8;
      const bf16x8s af = *(const bf16x8s*)(Alds + (wid * 16 + lr) * 64 + col);
      bf16x8s bfv[4];
#pragma unroll
      for (int n = 0; n < 4; ++n)
        bfv[n] = *(const bf16x8s*)(Blds + (n * 16 + lr) * 64 + col);
#pragma unroll
      for (int n = 0; n < 4; ++n)
        acc[n] = __builtin_amdgcn_mfma_f32_16x16x32_bf16(af, bfv[n], acc[n], 0, 0, 0);
    }
    __syncthreads();
  }
#pragma unroll
  for (int j = 0; j < 4; ++j) {
    const int gm = brow + wid * 16 + lg * 4 + j;
    float* rowp = outf + (size_t)gm * Dc + bcol;
#pragma unroll
    for (int n = 0; n < 4; ++n) rowp[n * 16 + lr] = acc[n][j];
  }
}

// ---------------- causal flash attention (v11: 4 waves = 2 q-halves x 2 kv-halves) --
// 1024 blocks (32 bh x 32 q-tiles of 64 rows, balanced map) x 256 thr.
// Wave (qh, kp): q-cols [qt*64+qh*32, +32), kv sub-tile [u*64+kp*32, +32).
// 16 waves/CU. Static-max softmax => partial (acc, l) additive: kp-pairs merge
// at the end via LDS. In-register P (cvt_pk + permlane32_swap).
__launch_bounds__(256, 4)
__global__ void attn_kernel(const __bf16* __restrict__ Q, const __bf16* __restrict__ K,
                            const __bf16* __restrict__ Vt, __bf16* __restrict__ O) {
  __shared__ __bf16 Klds[2][64 * 64];   // [kv][hd] rows 128B, XOR-swizzled key kv&7
  __shared__ __bf16 Vlds[2][64 * 64];   // [hd][kv] rows 128B, XOR-swizzled key hd&7
  const int f = blockIdx.x;
  const int xcd = f & 7, g = f >> 3;    // 128 blocks per XCD = 4 bh x 32 q-tiles
  const int pass = g >> 5, g5 = g & 31;
  const int bh = xcd * 4 + pass;
  const int qt = (pass & 1) ? (31 - g5) : g5;  // CU round-robin gets {c,31-c,c,31-c}
  const int tid = threadIdx.x;
  const int lane = tid & 63, wid = tid >> 6;
  const int qh = wid >> 1, kp = wid & 1;       // wave's q-half / kv-half
  const int q31 = lane & 31, hh = lane >> 5;   // lane's q-col / k(hd)-half
  const int k3 = q31 & 7;                      // row-XOR swizzle key
  const __bf16* Qp = Q + (size_t)bh * Tc * HDc;
  const char* Kb = (const char*)(K + (size_t)bh * Tc * HDc);
  const char* Vb = (const char*)(Vt + (size_t)bh * HDc * Tc);

  const int units = qt + 1;

  const int sr8 = wid * 8 + (lane >> 3);
  const int sxor = ((lane & 7) ^ ((lane >> 3) & 7)) << 4;  // pre-swizzled src col
  const char* vsrc = Vb + (size_t)sr8 * (Tc * 2) + sxor;

  const int q0w = qt * 64 + qh * 32;
  bf16x8s qf[4];
#pragma unroll
  for (int ks = 0; ks < 4; ++ks)
    qf[ks] = *(const bf16x8s*)(Qp + (q0w + q31) * HDc + ks * 16 + hh * 8);

  const int b = bh >> 4, h = bh & 15;

  f32x16 acc0 = {}, acc1 = {};
  float lsum = 0.f;

#define STAGE(IT, BUF)                                                                   \
  do {                                                                                   \
    _Pragma("unroll")                                                                    \
    for (int i_ = 0; i_ < 2; ++i_) {                                                     \
      __builtin_amdgcn_global_load_lds(                                                  \
          (gvoid_t*)(Kb + (size_t)((IT) * 64 + i_ * 32 + sr8) * 128 + sxor),             \
          (lvoid_t*)((char*)Klds[BUF] + i_ * 4096 + wid * 1024), 16, 0, 0);              \
      __builtin_amdgcn_global_load_lds(                                                  \
          (gvoid_t*)(vsrc + (size_t)i_ * 32 * (Tc * 2) + (IT) * 128),                    \
          (lvoid_t*)((char*)Vlds[BUF] + i_ * 4096 + wid * 1024), 16, 0, 0);              \
    }                                                                                    \
  } while (0)

  STAGE(0, 0);
  asm volatile("s_waitcnt vmcnt(0)" ::: "memory");
  __builtin_amdgcn_sched_barrier(0);
  __builtin_amdgcn_s_barrier();
  __builtin_amdgcn_sched_barrier(0);

  for (int u = 0; u < units; ++u) {
    if (u + 1 < units) STAGE(u + 1, (u + 1) & 1);
    __builtin_amdgcn_sched_barrier(0);

    const bool last = (u == qt);
    if (!last || qh == 1 || kp == 0) {  // wave(0,1) fully masked on diagonal
      const char* Kl = (const char*)Klds[u & 1];
      const char* Vl = (const char*)Vlds[u & 1];
      const bool fin = last && (qh == kp);        // diagonal waves (0,0),(1,1)
      const int thr = q0w + q31 - u * 64 - kp * 32 - 4 * hh;  // mask when 8n+j > thr

      bf16x8s kf[4];
#pragma unroll
      for (int ks = 0; ks < 4; ++ks)
        kf[ks] = *(const bf16x8s*)(Kl + (kp * 32 + q31) * 128 + (((2 * ks + hh) ^ k3) << 4));
      f32x16 z = {};
      __builtin_amdgcn_s_setprio(1);
#pragma unroll
      for (int ks = 0; ks < 4; ++ks)
        z = __builtin_amdgcn_mfma_f32_32x32x16_bf16(kf[ks], qf[ks], z, 0, 0, 0);
      __builtin_amdgcn_s_setprio(0);

      unsigned w0[4], w1[4];
#pragma unroll
      for (int n = 0; n < 4; ++n) {
        float e[4];
#pragma unroll
        for (int j = 0; j < 4; ++j) {
          float ev = __builtin_amdgcn_exp2f(z[n * 4 + j]);
          if (fin && (n * 8 + j > thr)) ev = 0.f;
          lsum += ev;
          e[j] = ev;
        }
        asm("v_cvt_pk_bf16_f32 %0, %1, %2" : "=v"(w0[n]) : "v"(e[0]), "v"(e[1]));
        asm("v_cvt_pk_bf16_f32 %0, %1, %2" : "=v"(w1[n]) : "v"(e[2]), "v"(e[3]));
      }

      bf16x8s pfr[2];
#pragma unroll
      for (int ks2 = 0; ks2 < 2; ++ks2) {
        unsigned a = w0[2 * ks2], bb2 = w0[2 * ks2 + 1];
        unsigned c = w1[2 * ks2], d = w1[2 * ks2 + 1];
        asm volatile("v_permlane32_swap_b32 %0, %1" : "+v"(a), "+v"(bb2));
        asm volatile("v_permlane32_swap_b32 %0, %1" : "+v"(c), "+v"(d));
        union { unsigned u[4]; bf16x8s v; } uu;
        uu.u[0] = a; uu.u[1] = c; uu.u[2] = bb2; uu.u[3] = d;
        pfr[ks2] = uu.v;
      }

      __builtin_amdgcn_s_setprio(1);
#pragma unroll
      for (int ks2 = 0; ks2 < 2; ++ks2) {
        const int so = ((kp * 4 + 2 * ks2 + hh) ^ k3) << 4;
        const bf16x8s va0 = *(const bf16x8s*)(Vl + q31 * 128 + so);
        const bf16x8s va1 = *(const bf16x8s*)(Vl + (32 + q31) * 128 + so);
        acc0 = __builtin_amdgcn_mfma_f32_32x32x16_bf16(va0, pfr[ks2], acc0, 0, 0, 0);
        acc1 = __builtin_amdgcn_mfma_f32_32x32x16_bf16(va1, pfr[ks2], acc1, 0, 0, 0);
      }
      __builtin_amdgcn_s_setprio(0);
    }

    if (u + 1 < units) {
      asm volatile("s_waitcnt vmcnt(0)" ::: "memory");  // stage(u+1) landed
      __builtin_amdgcn_sched_barrier(0);
      __builtin_amdgcn_s_barrier();  // all waves done with buf[u&1]; buf[(u+1)&1] ready
      __builtin_amdgcn_sched_barrier(0);
    }
  }
#undef STAGE

  // ---- kp-pair combine (static max => additive), then finalize ----
  __syncthreads();  // all K/V reads done; buffers become scratch
  float* tp = (qh == 0) ? (float*)(&Klds[0][0]) : (float*)(&Vlds[0][0]);
  if (kp == 1) {
#pragma unroll
    for (int i = 0; i < 16; ++i) {
      tp[i * 64 + lane] = acc0[i];
      tp[1024 + i * 64 + lane] = acc1[i];
    }
    tp[2048 + lane] = lsum;
  }
  __syncthreads();
  if (kp == 0) {
#pragma unroll
    for (int i = 0; i < 16; ++i) {
      acc0[i] += tp[i * 64 + lane];
      acc1[i] += tp[1024 + i * 64 + lane];
    }
    lsum += tp[2048 + lane];
    const float lt = lsum + __shfl_xor(lsum, 32);
    const float linv = 1.f / lt;
    const int t = q0w + q31;
    __bf16* dst = O + ((size_t)b * Tc + t) * Dc + h * HDc;
#pragma unroll
    for (int qd = 0; qd < 4; ++qd) {
      bf16x4 o0, o1;
#pragma unroll
      for (int j = 0; j < 4; ++j) {
        o0[j] = (__bf16)(acc0[qd * 4 + j] * linv);
        o1[j] = (__bf16)(acc1[qd * 4 + j] * linv);
      }
      *(bf16x4*)(dst + qd * 8 + hh * 4) = o0;
      *(bf16x4*)(dst + 32 + qd * 8 + hh * 4) = o1;
    }
  }
}

// ---------------- launch ----------------
extern "C" void kernel_launch(void* const* d_in, const int* in_sizes, int n_in,
                              void* d_out, int out_size, void* d_ws, size_t ws_size,
                              hipStream_t stream) {
  const float* x   = (const float*)d_in[0];
  const float* cbt = (const float*)d_in[1];
  const float* sbt = (const float*)d_in[2];
  const float* Wq  = (const float*)d_in[3];
  const float* Wk  = (const float*)d_in[4];
  const float* Wv  = (const float*)d_in[5];
  const float* Wp  = (const float*)d_in[6];
  float* out = (float*)d_out;
  char* ws = (char*)d_ws;
  __bf16* xb = (__bf16*)(ws);
  __bf16* wb = (__bf16*)(ws + (8u << 20));
  __bf16* qb = (__bf16*)(ws + (16u << 20));
  __bf16* vt = (__bf16*)(ws + (40u << 20));
  __bf16* ao = (__bf16*)(ws + (48u << 20));
  __bf16* kb = qb + (size_t)Mc * Dc;

  cvt_all<<<8192, 256, 0, stream>>>(x, Wq, Wk, Wv, Wp, xb, wb);
  gemm_qkv<<<dim3(16, 32, 3), 256, 0, stream>>>(xb, wb, qb, vt, cbt, sbt);
  attn_kernel<<<1024, 256, 0, stream>>>(qb, kb, vt, ao);
  gemm_proj<<<1024, 256, 0, stream>>>(ao, wb + 3u * (Dc * Dc), out);
}

// Round 13
// 104.140 us; speedup vs baseline: 1.0738x; 1.0738x over previous
//
#include <hip/hip_runtime.h>
#include <hip/hip_bf16.h>

typedef __attribute__((ext_vector_type(8))) short bf16x8s;   // 8 bf16 as shorts (MFMA frag)
typedef __attribute__((ext_vector_type(4))) float f32x4;
typedef __attribute__((ext_vector_type(16))) float f32x16;
typedef __attribute__((ext_vector_type(4))) __bf16 bf16x4;
typedef __attribute__((ext_vector_type(8))) __bf16 bf16x8;

typedef const __attribute__((address_space(1))) void gvoid_t;
typedef __attribute__((address_space(3))) void lvoid_t;

constexpr int Bc = 2, Tc = 2048, Dc = 1024, Hc = 16, HDc = 64;
constexpr int Mc = Bc * Tc;  // 4096

// ---------------- fused fp32 -> bf16 convert: x (4096 blocks) + 4 weights (4096) ----
__global__ void cvt_all(const float* __restrict__ x,
                        const float* __restrict__ wq, const float* __restrict__ wk,
                        const float* __restrict__ wv, const float* __restrict__ wp,
                        __bf16* __restrict__ xb, __bf16* __restrict__ wb) {
  const int bid = blockIdx.x;
  const float* src;
  __bf16* dst;
  int i;
  if (bid < 4096) {
    src = x; dst = xb; i = (bid * 256 + threadIdx.x) * 4;
  } else {
    const int r = bid - 4096;
    const int w = r >> 10;
    src = (w == 0) ? wq : (w == 1) ? wk : (w == 2) ? wv : wp;
    dst = wb + (size_t)w * (Dc * Dc);
    i = ((r & 1023) * 256 + threadIdx.x) * 4;
  }
  float4 v = *(const float4*)(src + i);
  bf16x4 o;
  o[0] = (__bf16)v.x; o[1] = (__bf16)v.y; o[2] = (__bf16)v.z; o[3] = (__bf16)v.w;
  *(bf16x4*)(dst + i) = o;
}

// ---------------- QKV GEMM (v3): 128x128 tile, SWAPPED mfma operands ---------------
// acc[m][n] = mfma(bfv[n], af[m]): reg dim = N (4 consecutive cols per thread),
// lane dim = M. Enables bf16x4 packed stores + float4 RoPE table loads.
// z=0: RoPE+score-scale; z=1: RoPE; z=2: V^T LDS-bounce -> vt [B,H,HD,T].
__launch_bounds__(256, 2)
__global__ void gemm_qkv(const __bf16* __restrict__ A,
                         const __bf16* __restrict__ W,
                         __bf16* __restrict__ outb,
                         __bf16* __restrict__ vtout,
                         const float* __restrict__ cbt,
                         const float* __restrict__ sbt) {
  __shared__ __bf16 smem[2][128 * 64];
  __bf16* Alds = smem[0];
  __bf16* Blds = smem[1];
  const int tid = threadIdx.x;
  const int lane = tid & 63, wid = tid >> 6;
  const int wr = wid >> 1, wc = wid & 1;
  const int lr = lane & 15, lg = lane >> 4;
  // XCD-chunked remap: each XCD owns 4 M-rows x 8 N-cols (1MB A + 2MB B in its L2)
  const int lid = blockIdx.x + (int)gridDim.x * blockIdx.y;
  const int xcd = lid & 7, g = lid >> 3;
  const int brow = (xcd * 4 + (g & 3)) * 128;
  const int bcol = (g >> 2) * 128;
  const int z = blockIdx.z;
  const __bf16* Wm = W + (size_t)z * (Dc * Dc);

  f32x4 acc[4][4] = {};   // [m 16-row grp][n 16-col grp]; j = col offset, lr = row

  const char* Ag = (const char*)(A + (size_t)brow * Dc);
  const char* Bg = (const char*)(Wm + (size_t)bcol * Dc);
  const int r0 = tid >> 3;
  const int cb = (tid & 7) * 16;

  for (int k0 = 0; k0 < Dc; k0 += 64) {
#pragma unroll
    for (int i = 0; i < 4; ++i) {
      const int r = i * 32 + r0;
      const int ldsoff = (i * 256 + wid * 64) * 16;
      __builtin_amdgcn_global_load_lds(
          (gvoid_t*)(Ag + (size_t)r * (Dc * 2) + k0 * 2 + cb),
          (lvoid_t*)((char*)Alds + ldsoff), 16, 0, 0);
      __builtin_amdgcn_global_load_lds(
          (gvoid_t*)(Bg + (size_t)r * (Dc * 2) + k0 * 2 + cb),
          (lvoid_t*)((char*)Blds + ldsoff), 16, 0, 0);
    }
    __syncthreads();
#pragma unroll
    for (int kk = 0; kk < 2; ++kk) {
      const int col = kk * 32 + lg * 8;
      bf16x8s af[4], bfv[4];
#pragma unroll
      for (int m = 0; m < 4; ++m)
        af[m] = *(const bf16x8s*)(Alds + (wr * 64 + m * 16 + lr) * 64 + col);
#pragma unroll
      for (int n = 0; n < 4; ++n)
        bfv[n] = *(const bf16x8s*)(Blds + (wc * 64 + n * 16 + lr) * 64 + col);
#pragma unroll
      for (int m = 0; m < 4; ++m)
#pragma unroll
        for (int n = 0; n < 4; ++n)
          acc[m][n] = __builtin_amdgcn_mfma_f32_16x16x32_bf16(bfv[n], af[m], acc[m][n], 0, 0, 0);
    }
    __syncthreads();
  }

  if (z == 2) {
    // V^T epilogue: C^T via LDS [64 hd][136 t], coalesced 16B stores to vt
    const int bb = brow >> 11, t0b = brow & (Tc - 1);
    __bf16* tile_t = smem[0];
#pragma unroll
    for (int h2 = 0; h2 < 2; ++h2) {
      __syncthreads();
      if (wc == h2) {
        // thread holds hd = n*16+lg*4+j (4 consecutive) at t-in-tile = wr*64+m*16+lr
#pragma unroll
        for (int n = 0; n < 4; ++n)
#pragma unroll
          for (int m = 0; m < 4; ++m)
#pragma unroll
            for (int j = 0; j < 4; ++j)
              tile_t[(n * 16 + lg * 4 + j) * 136 + wr * 64 + m * 16 + lr] = (__bf16)acc[m][n][j];
      }
      __syncthreads();
      const int h = (bcol >> 6) + h2;
#pragma unroll
      for (int pass = 0; pass < 4; ++pass) {
        const int r = pass * 16 + (tid >> 4);
        const int c8 = (tid & 15) * 8;
        bf16x8 vvv = *(const bf16x8*)(tile_t + r * 136 + c8);
        *(bf16x8*)(vtout + (((size_t)bb * Hc + h) * HDc + r) * Tc + t0b + c8) = vvv;
      }
    }
    return;
  }

  // z==0/1: fused RoPE (+ score scale for Q), packed bf16x4 stores to [B,H,T,HD]
  {
    const float scl = (z == 0) ? 0.18033688011112042f : 1.0f;  // (1/8)*log2(e)
    const int h = (bcol >> 6) + wc;
    __bf16* dst = outb + (size_t)z * ((size_t)Mc * Dc);
#pragma unroll
    for (int m = 0; m < 4; ++m) {
      const int gm = brow + wr * 64 + m * 16 + lr;
      const int bb = gm >> 11, t = gm & (Tc - 1);
      const float* cbase = cbt + (size_t)gm * HDc;
      const float* sbase = sbt + (size_t)gm * HDc;
#pragma unroll
      for (int n = 0; n < 2; ++n) {
        const float4 cv = *(const float4*)(cbase + n * 16 + lg * 4);  // c[i+32]==c[i]
        const float4 sv = *(const float4*)(sbase + n * 16 + lg * 4);
        const float cc[4] = {cv.x, cv.y, cv.z, cv.w};
        const float ss[4] = {sv.x, sv.y, sv.z, sv.w};
#pragma unroll
        for (int j = 0; j < 4; ++j) {
          const float v0 = acc[m][n][j], v1 = acc[m][n + 2][j];
          acc[m][n][j]     = (v0 * cc[j] - v1 * ss[j]) * scl;
          acc[m][n + 2][j] = (v1 * cc[j] + v0 * ss[j]) * scl;
        }
      }
      __bf16* rowp = dst + (((size_t)bb * Hc + h) * Tc + t) * HDc;
#pragma unroll
      for (int n = 0; n < 4; ++n) {
        bf16x4 pb;
#pragma unroll
        for (int j = 0; j < 4; ++j) pb[j] = (__bf16)acc[m][n][j];
        *(bf16x4*)(rowp + n * 16 + lg * 4) = pb;
      }
    }
  }
}

// ---------------- output projection GEMM (v3): 128x64, swapped mfma, float4 stores --
__launch_bounds__(256, 2)
__global__ void gemm_proj(const __bf16* __restrict__ A, const __bf16* __restrict__ W,
                          float* __restrict__ outf) {
  __shared__ __bf16 Alds[128 * 64];
  __shared__ __bf16 Blds[64 * 64];
  const int tid = threadIdx.x;
  const int lane = tid & 63, wid = tid >> 6;
  const int lr = lane & 15, lg = lane >> 4;
  const int lid = blockIdx.x + (int)gridDim.x * blockIdx.y;  // 512 blocks
  const int xcd = lid & 7, g = lid >> 3;
  const int brow = (xcd * 4 + (g & 3)) * 128;
  const int bcol = (g >> 2) * 64;
  f32x4 acc[2][4] = {};
  const char* Ag = (const char*)(A + (size_t)brow * Dc);
  const char* Bg = (const char*)(W + (size_t)bcol * Dc);
  const int r0 = tid >> 3;
  const int cb = (tid & 7) * 16;
  for (int k0 = 0; k0 < Dc; k0 += 64) {
#pragma unroll
    for (int i = 0; i < 4; ++i) {
      const int r = i * 32 + r0;
      const int ldsoff = (i * 256 + wid * 64) * 16;
      __builtin_amdgcn_global_load_lds(
          (gvoid_t*)(Ag + (size_t)r * (Dc * 2) + k0 * 2 + cb),
          (lvoid_t*)((char*)Alds + ldsoff), 16, 0, 0);
    }
#pragma unroll
    for (int i = 0; i < 2; ++i) {
      const int r = i * 32 + r0;
      const int ldsoff = (i * 256 + wid * 64) * 16;
      __builtin_amdgcn_global_load_lds(
          (gvoid_t*)(Bg + (size_t)r * (Dc * 2) + k0 * 2 + cb),
          (lvoid_t*)((char*)Blds + ldsoff), 16, 0, 0);
    }
    __syncthreads();
#pragma unroll
    for (int kk = 0; kk < 2; ++kk) {
      const int col = kk * 32 + lg * 8;
      bf16x8s af[2], bfv[4];
#pragma unroll
      for (int m = 0; m < 2; ++m)
        af[m] = *(const bf16x8s*)(Alds + (wid * 32 + m * 16 + lr) * 64 + col);
#pragma unroll
      for (int n = 0; n < 4; ++n)
        bfv[n] = *(const bf16x8s*)(Blds + (n * 16 + lr) * 64 + col);
#pragma unroll
      for (int m = 0; m < 2; ++m)
#pragma unroll
        for (int n = 0; n < 4; ++n)
          acc[m][n] = __builtin_amdgcn_mfma_f32_16x16x32_bf16(bfv[n], af[m], acc[m][n], 0, 0, 0);
    }
    __syncthreads();
  }
#pragma unroll
  for (int m = 0; m < 2; ++m) {
    const int gm = brow + wid * 32 + m * 16 + lr;
    float* rowp = outf + (size_t)gm * Dc + bcol;
#pragma unroll
    for (int n = 0; n < 4; ++n) {
      float4 fv;
      fv.x = acc[m][n][0]; fv.y = acc[m][n][1]; fv.z = acc[m][n][2]; fv.w = acc[m][n][3];
      *(float4*)(rowp + n * 16 + lg * 4) = fv;
    }
  }
}

// ---------------- causal flash attention (v11: 4 waves = 2 q-halves x 2 kv-halves) --
// 1024 blocks (32 bh x 32 q-tiles of 64 rows, balanced map) x 256 thr.
// Wave (qh, kp): q-cols [qt*64+qh*32, +32), kv sub-tile [u*64+kp*32, +32).
// 16 waves/CU. Static-max softmax => partial (acc, l) additive: kp-pairs merge
// at the end via LDS. In-register P (cvt_pk + permlane32_swap).
__launch_bounds__(256, 4)
__global__ void attn_kernel(const __bf16* __restrict__ Q, const __bf16* __restrict__ K,
                            const __bf16* __restrict__ Vt, __bf16* __restrict__ O) {
  __shared__ __bf16 Klds[2][64 * 64];   // [kv][hd] rows 128B, XOR-swizzled key kv&7
  __shared__ __bf16 Vlds[2][64 * 64];   // [hd][kv] rows 128B, XOR-swizzled key hd&7
  const int f = blockIdx.x;
  const int xcd = f & 7, g = f >> 3;    // 128 blocks per XCD = 4 bh x 32 q-tiles
  const int pass = g >> 5, g5 = g & 31;
  const int bh = xcd * 4 + pass;
  const int qt = (pass & 1) ? (31 - g5) : g5;  // CU round-robin gets {c,31-c,c,31-c}
  const int tid = threadIdx.x;
  const int lane = tid & 63, wid = tid >> 6;
  const int qh = wid >> 1, kp = wid & 1;       // wave's q-half / kv-half
  const int q31 = lane & 31, hh = lane >> 5;   // lane's q-col / k(hd)-half
  const int k3 = q31 & 7;                      // row-XOR swizzle key
  const __bf16* Qp = Q + (size_t)bh * Tc * HDc;
  const char* Kb = (const char*)(K + (size_t)bh * Tc * HDc);
  const char* Vb = (const char*)(Vt + (size_t)bh * HDc * Tc);

  const int units = qt + 1;

  const int sr8 = wid * 8 + (lane >> 3);
  const int sxor = ((lane & 7) ^ ((lane >> 3) & 7)) << 4;  // pre-swizzled src col
  const char* vsrc = Vb + (size_t)sr8 * (Tc * 2) + sxor;

  const int q0w = qt * 64 + qh * 32;
  bf16x8s qf[4];
#pragma unroll
  for (int ks = 0; ks < 4; ++ks)
    qf[ks] = *(const bf16x8s*)(Qp + (q0w + q31) * HDc + ks * 16 + hh * 8);

  const int b = bh >> 4, h = bh & 15;

  f32x16 acc0 = {}, acc1 = {};
  float lsum = 0.f;

#define STAGE(IT, BUF)                                                                   \
  do {                                                                                   \
    _Pragma("unroll")                                                                    \
    for (int i_ = 0; i_ < 2; ++i_) {                                                     \
      __builtin_amdgcn_global_load_lds(                                                  \
          (gvoid_t*)(Kb + (size_t)((IT) * 64 + i_ * 32 + sr8) * 128 + sxor),             \
          (lvoid_t*)((char*)Klds[BUF] + i_ * 4096 + wid * 1024), 16, 0, 0);              \
      __builtin_amdgcn_global_load_lds(                                                  \
          (gvoid_t*)(vsrc + (size_t)i_ * 32 * (Tc * 2) + (IT) * 128),                    \
          (lvoid_t*)((char*)Vlds[BUF] + i_ * 4096 + wid * 1024), 16, 0, 0);              \
    }                                                                                    \
  } while (0)

  STAGE(0, 0);
  asm volatile("s_waitcnt vmcnt(0)" ::: "memory");
  __builtin_amdgcn_sched_barrier(0);
  __builtin_amdgcn_s_barrier();
  __builtin_amdgcn_sched_barrier(0);

  for (int u = 0; u < units; ++u) {
    if (u + 1 < units) STAGE(u + 1, (u + 1) & 1);
    __builtin_amdgcn_sched_barrier(0);

    const bool last = (u == qt);
    if (!last || qh == 1 || kp == 0) {  // wave(0,1) fully masked on diagonal
      const char* Kl = (const char*)Klds[u & 1];
      const char* Vl = (const char*)Vlds[u & 1];
      const bool fin = last && (qh == kp);        // diagonal waves (0,0),(1,1)
      const int thr = q0w + q31 - u * 64 - kp * 32 - 4 * hh;  // mask when 8n+j > thr

      bf16x8s kf[4];
#pragma unroll
      for (int ks = 0; ks < 4; ++ks)
        kf[ks] = *(const bf16x8s*)(Kl + (kp * 32 + q31) * 128 + (((2 * ks + hh) ^ k3) << 4));
      f32x16 z = {};
      __builtin_amdgcn_s_setprio(1);
#pragma unroll
      for (int ks = 0; ks < 4; ++ks)
        z = __builtin_amdgcn_mfma_f32_32x32x16_bf16(kf[ks], qf[ks], z, 0, 0, 0);
      __builtin_amdgcn_s_setprio(0);

      unsigned w0[4], w1[4];
#pragma unroll
      for (int n = 0; n < 4; ++n) {
        float e[4];
#pragma unroll
        for (int j = 0; j < 4; ++j) {
          float ev = __builtin_amdgcn_exp2f(z[n * 4 + j]);
          if (fin && (n * 8 + j > thr)) ev = 0.f;
          lsum += ev;
          e[j] = ev;
        }
        asm("v_cvt_pk_bf16_f32 %0, %1, %2" : "=v"(w0[n]) : "v"(e[0]), "v"(e[1]));
        asm("v_cvt_pk_bf16_f32 %0, %1, %2" : "=v"(w1[n]) : "v"(e[2]), "v"(e[3]));
      }

      bf16x8s pfr[2];
#pragma unroll
      for (int ks2 = 0; ks2 < 2; ++ks2) {
        unsigned a = w0[2 * ks2], bb2 = w0[2 * ks2 + 1];
        unsigned c = w1[2 * ks2], d = w1[2 * ks2 + 1];
        asm volatile("v_permlane32_swap_b32 %0, %1" : "+v"(a), "+v"(bb2));
        asm volatile("v_permlane32_swap_b32 %0, %1" : "+v"(c), "+v"(d));
        union { unsigned u[4]; bf16x8s v; } uu;
        uu.u[0] = a; uu.u[1] = c; uu.u[2] = bb2; uu.u[3] = d;
        pfr[ks2] = uu.v;
      }

      __builtin_amdgcn_s_setprio(1);
#pragma unroll
      for (int ks2 = 0; ks2 < 2; ++ks2) {
        const int so = ((kp * 4 + 2 * ks2 + hh) ^ k3) << 4;
        const bf16x8s va0 = *(const bf16x8s*)(Vl + q31 * 128 + so);
        const bf16x8s va1 = *(const bf16x8s*)(Vl + (32 + q31) * 128 + so);
        acc0 = __builtin_amdgcn_mfma_f32_32x32x16_bf16(va0, pfr[ks2], acc0, 0, 0, 0);
        acc1 = __builtin_amdgcn_mfma_f32_32x32x16_bf16(va1, pfr[ks2], acc1, 0, 0, 0);
      }
      __builtin_amdgcn_s_setprio(0);
    }

    if (u + 1 < units) {
      asm volatile("s_waitcnt vmcnt(0)" ::: "memory");  // stage(u+1) landed
      __builtin_amdgcn_sched_barrier(0);
      __builtin_amdgcn_s_barrier();  // all waves done with buf[u&1]; buf[(u+1)&1] ready
      __builtin_amdgcn_sched_barrier(0);
    }
  }
#undef STAGE

  // ---- kp-pair combine (static max => additive), then finalize ----
  __syncthreads();  // all K/V reads done; buffers become scratch
  float* tp = (qh == 0) ? (float*)(&Klds[0][0]) : (float*)(&Vlds[0][0]);
  if (kp == 1) {
#pragma unroll
    for (int i = 0; i < 16; ++i) {
      tp[i * 64 + lane] = acc0[i];
      tp[1024 + i * 64 + lane] = acc1[i];
    }
    tp[2048 + lane] = lsum;
  }
  __syncthreads();
  if (kp == 0) {
#pragma unroll
    for (int i = 0; i < 16; ++i) {
      acc0[i] += tp[i * 64 + lane];
      acc1[i] += tp[1024 + i * 64 + lane];
    }
    lsum += tp[2048 + lane];
    const float lt = lsum + __shfl_xor(lsum, 32);
    const float linv = 1.f / lt;
    const int t = q0w + q31;
    __bf16* dst = O + ((size_t)b * Tc + t) * Dc + h * HDc;
#pragma unroll
    for (int qd = 0; qd < 4; ++qd) {
      bf16x4 o0, o1;
#pragma unroll
      for (int j = 0; j < 4; ++j) {
        o0[j] = (__bf16)(acc0[qd * 4 + j] * linv);
        o1[j] = (__bf16)(acc1[qd * 4 + j] * linv);
      }
      *(bf16x4*)(dst + qd * 8 + hh * 4) = o0;
      *(bf16x4*)(dst + 32 + qd * 8 + hh * 4) = o1;
    }
  }
}

// ---------------- launch ----------------
extern "C" void kernel_launch(void* const* d_in, const int* in_sizes, int n_in,
                              void* d_out, int out_size, void* d_ws, size_t ws_size,
                              hipStream_t stream) {
  const float* x   = (const float*)d_in[0];
  const float* cbt = (const float*)d_in[1];
  const float* sbt = (const float*)d_in[2];
  const float* Wq  = (const float*)d_in[3];
  const float* Wk  = (const float*)d_in[4];
  const float* Wv  = (const float*)d_in[5];
  const float* Wp  = (const float*)d_in[6];
  float* out = (float*)d_out;
  char* ws = (char*)d_ws;
  __bf16* xb = (__bf16*)(ws);
  __bf16* wb = (__bf16*)(ws + (8u << 20));
  __bf16* qb = (__bf16*)(ws + (16u << 20));
  __bf16* vt = (__bf16*)(ws + (40u << 20));
  __bf16* ao = (__bf16*)(ws + (48u << 20));
  __bf16* kb = qb + (size_t)Mc * Dc;

  cvt_all<<<8192, 256, 0, stream>>>(x, Wq, Wk, Wv, Wp, xb, wb);
  gemm_qkv<<<dim3(8, 32, 3), 256, 0, stream>>>(xb, wb, qb, vt, cbt, sbt);
  attn_kernel<<<1024, 256, 0, stream>>>(qb, kb, vt, ao);
  gemm_proj<<<dim3(16, 32), 256, 0, stream>>>(ao, wb + 3u * (Dc * Dc), out);
}

// Round 14
// 95.299 us; speedup vs baseline: 1.1735x; 1.0928x over previous
//
#include <hip/hip_runtime.h>
#include <hip/hip_bf16.h>

typedef __attribute__((ext_vector_type(8))) short bf16x8s;   // 8 bf16 as shorts (MFMA frag)
typedef __attribute__((ext_vector_type(4))) float f32x4;
typedef __attribute__((ext_vector_type(16))) float f32x16;
typedef __attribute__((ext_vector_type(4))) __bf16 bf16x4;
typedef __attribute__((ext_vector_type(8))) __bf16 bf16x8;

typedef const __attribute__((address_space(1))) void gvoid_t;
typedef __attribute__((address_space(3))) void lvoid_t;

constexpr int Bc = 2, Tc = 2048, Dc = 1024, Hc = 16, HDc = 64;
constexpr int Mc = Bc * Tc;  // 4096

// ---------------- fused fp32 -> bf16 convert: x (4096 blocks) + 4 weights (4096) ----
__global__ void cvt_all(const float* __restrict__ x,
                        const float* __restrict__ wq, const float* __restrict__ wk,
                        const float* __restrict__ wv, const float* __restrict__ wp,
                        __bf16* __restrict__ xb, __bf16* __restrict__ wb) {
  const int bid = blockIdx.x;
  const float* src;
  __bf16* dst;
  int i;
  if (bid < 4096) {
    src = x; dst = xb; i = (bid * 256 + threadIdx.x) * 4;
  } else {
    const int r = bid - 4096;
    const int w = r >> 10;
    src = (w == 0) ? wq : (w == 1) ? wk : (w == 2) ? wv : wp;
    dst = wb + (size_t)w * (Dc * Dc);
    i = ((r & 1023) * 256 + threadIdx.x) * 4;
  }
  float4 v = *(const float4*)(src + i);
  bf16x4 o;
  o[0] = (__bf16)v.x; o[1] = (__bf16)v.y; o[2] = (__bf16)v.z; o[3] = (__bf16)v.w;
  *(bf16x4*)(dst + i) = o;
}

// ---------------- QKV GEMM (r11-proven form + cos-symmetry): 128x128 tiles ---------
// z=0: RoPE+score-scale -> [B,H,T,HD]; z=1: RoPE -> [B,H,T,HD];
// z=2: V^T epilogue (LDS transpose bounce) -> vt [B,H,HD,T]
__launch_bounds__(256, 2)
__global__ void gemm_qkv(const __bf16* __restrict__ A,
                         const __bf16* __restrict__ W,
                         __bf16* __restrict__ outb,
                         __bf16* __restrict__ vtout,
                         const float* __restrict__ cbt,
                         const float* __restrict__ sbt) {
  __shared__ __bf16 smem[2][128 * 64];
  __bf16* Alds = smem[0];
  __bf16* Blds = smem[1];
  const int tid = threadIdx.x;
  const int lane = tid & 63, wid = tid >> 6;
  const int wr = wid >> 1, wc = wid & 1;
  const int lr = lane & 15, lg = lane >> 4;
  const int lid = blockIdx.x + (int)gridDim.x * blockIdx.y;
  const int xcd = lid & 7, g = lid >> 3;
  const int brow = (xcd * 4 + (g & 3)) * 128;
  const int bcol = (g >> 2) * 128;
  const __bf16* Wm = W + (size_t)blockIdx.z * (Dc * Dc);

  f32x4 acc[4][4] = {};

  const char* Ag = (const char*)(A + (size_t)brow * Dc);
  const char* Bg = (const char*)(Wm + (size_t)bcol * Dc);
  const int r0 = tid >> 3;
  const int cb = (tid & 7) * 16;

  for (int k0 = 0; k0 < Dc; k0 += 64) {
#pragma unroll
    for (int i = 0; i < 4; ++i) {
      const int r = i * 32 + r0;
      const int ldsoff = (i * 256 + wid * 64) * 16;
      __builtin_amdgcn_global_load_lds(
          (gvoid_t*)(Ag + (size_t)r * (Dc * 2) + k0 * 2 + cb),
          (lvoid_t*)((char*)Alds + ldsoff), 16, 0, 0);
      __builtin_amdgcn_global_load_lds(
          (gvoid_t*)(Bg + (size_t)r * (Dc * 2) + k0 * 2 + cb),
          (lvoid_t*)((char*)Blds + ldsoff), 16, 0, 0);
    }
    __syncthreads();
#pragma unroll
    for (int kk = 0; kk < 2; ++kk) {
      const int col = kk * 32 + lg * 8;
      bf16x8s af[4], bfv[4];
#pragma unroll
      for (int m = 0; m < 4; ++m)
        af[m] = *(const bf16x8s*)(Alds + (wr * 64 + m * 16 + lr) * 64 + col);
#pragma unroll
      for (int n = 0; n < 4; ++n)
        bfv[n] = *(const bf16x8s*)(Blds + (wc * 64 + n * 16 + lr) * 64 + col);
#pragma unroll
      for (int m = 0; m < 4; ++m)
#pragma unroll
        for (int n = 0; n < 4; ++n)
          acc[m][n] = __builtin_amdgcn_mfma_f32_16x16x32_bf16(af[m], bfv[n], acc[m][n], 0, 0, 0);
    }
    __syncthreads();
  }

  const int z = blockIdx.z;
  if (z == 2) {
    // V^T epilogue: stage C^T halves in LDS, coalesced store to vt [B,H,HD,T]
    const int bb = brow >> 11, t0b = brow & (Tc - 1);
    __bf16* tile_t = smem[0];  // [64][136]
#pragma unroll
    for (int h2 = 0; h2 < 2; ++h2) {
      __syncthreads();
      if (wc == h2) {
#pragma unroll
        for (int n = 0; n < 4; ++n) {
#pragma unroll
          for (int m = 0; m < 4; ++m) {
            bf16x4 pb;
#pragma unroll
            for (int j = 0; j < 4; ++j) pb[j] = (__bf16)acc[m][n][j];
            *(bf16x4*)(tile_t + (n * 16 + lr) * 136 + wr * 64 + m * 16 + lg * 4) = pb;
          }
        }
      }
      __syncthreads();
#pragma unroll
      for (int pass = 0; pass < 4; ++pass) {
        const int r = pass * 16 + (tid >> 4);
        const int c8 = (tid & 15) * 8;
        bf16x8 vvv = *(const bf16x8*)(tile_t + r * 136 + c8);
        const int gn = bcol + h2 * 64 + r;
        const int h = gn >> 6, hd = gn & 63;
        *(bf16x8*)(vtout + (((size_t)bb * Hc + h) * HDc + hd) * Tc + t0b + c8) = vvv;
      }
    }
    return;
  }

  // z==0/1: fused RoPE (+ score scale for Q); cos[i+32]==cos[i] halves table loads
  {
    const float scl = (z == 0) ? 0.18033688011112042f : 1.0f;  // (1/8)*log2(e)
#pragma unroll
    for (int m = 0; m < 4; ++m) {
#pragma unroll
      for (int j = 0; j < 4; ++j) {
        const int gm = brow + wr * 64 + m * 16 + lg * 4 + j;
        const float* cbase = cbt + (size_t)gm * HDc;
        const float* sbase = sbt + (size_t)gm * HDc;
#pragma unroll
        for (int n = 0; n < 2; ++n) {
          const int i = n * 16 + lr;
          const float c0 = cbase[i], s0 = sbase[i];
          const float v0 = acc[m][n][j], v1 = acc[m][n + 2][j];
          acc[m][n][j]     = (v0 * c0 - v1 * s0) * scl;
          acc[m][n + 2][j] = (v1 * c0 + v0 * s0) * scl;
        }
      }
    }
    __bf16* dst = outb + (size_t)z * ((size_t)Mc * Dc);
#pragma unroll
    for (int m = 0; m < 4; ++m) {
#pragma unroll
      for (int j = 0; j < 4; ++j) {
        const int gm = brow + wr * 64 + m * 16 + lg * 4 + j;
        const int bb = gm >> 11, t = gm & (Tc - 1);
#pragma unroll
        for (int n = 0; n < 4; ++n) {
          const int gn = bcol + wc * 64 + n * 16 + lr;
          const int h = gn >> 6, hd = gn & 63;
          dst[(((size_t)bb * Hc + h) * Tc + t) * HDc + hd] = (__bf16)acc[m][n][j];
        }
      }
    }
  }
}

// ---------------- output projection GEMM: 128x64, swapped mfma, float4 stores -------
__launch_bounds__(256, 2)
__global__ void gemm_proj(const __bf16* __restrict__ A, const __bf16* __restrict__ W,
                          float* __restrict__ outf) {
  __shared__ __bf16 Alds[128 * 64];
  __shared__ __bf16 Blds[64 * 64];
  const int tid = threadIdx.x;
  const int lane = tid & 63, wid = tid >> 6;
  const int lr = lane & 15, lg = lane >> 4;
  const int lid = blockIdx.x + (int)gridDim.x * blockIdx.y;  // 512 blocks
  const int xcd = lid & 7, g = lid >> 3;
  const int brow = (xcd * 4 + (g & 3)) * 128;
  const int bcol = (g >> 2) * 64;
  f32x4 acc[2][4] = {};
  const char* Ag = (const char*)(A + (size_t)brow * Dc);
  const char* Bg = (const char*)(W + (size_t)bcol * Dc);
  const int r0 = tid >> 3;
  const int cb = (tid & 7) * 16;
  for (int k0 = 0; k0 < Dc; k0 += 64) {
#pragma unroll
    for (int i = 0; i < 4; ++i) {
      const int r = i * 32 + r0;
      const int ldsoff = (i * 256 + wid * 64) * 16;
      __builtin_amdgcn_global_load_lds(
          (gvoid_t*)(Ag + (size_t)r * (Dc * 2) + k0 * 2 + cb),
          (lvoid_t*)((char*)Alds + ldsoff), 16, 0, 0);
    }
#pragma unroll
    for (int i = 0; i < 2; ++i) {
      const int r = i * 32 + r0;
      const int ldsoff = (i * 256 + wid * 64) * 16;
      __builtin_amdgcn_global_load_lds(
          (gvoid_t*)(Bg + (size_t)r * (Dc * 2) + k0 * 2 + cb),
          (lvoid_t*)((char*)Blds + ldsoff), 16, 0, 0);
    }
    __syncthreads();
#pragma unroll
    for (int kk = 0; kk < 2; ++kk) {
      const int col = kk * 32 + lg * 8;
      bf16x8s af[2], bfv[4];
#pragma unroll
      for (int m = 0; m < 2; ++m)
        af[m] = *(const bf16x8s*)(Alds + (wid * 32 + m * 16 + lr) * 64 + col);
#pragma unroll
      for (int n = 0; n < 4; ++n)
        bfv[n] = *(const bf16x8s*)(Blds + (n * 16 + lr) * 64 + col);
#pragma unroll
      for (int m = 0; m < 2; ++m)
#pragma unroll
        for (int n = 0; n < 4; ++n)
          acc[m][n] = __builtin_amdgcn_mfma_f32_16x16x32_bf16(bfv[n], af[m], acc[m][n], 0, 0, 0);
    }
    __syncthreads();
  }
#pragma unroll
  for (int m = 0; m < 2; ++m) {
    const int gm = brow + wid * 32 + m * 16 + lr;
    float* rowp = outf + (size_t)gm * Dc + bcol;
#pragma unroll
    for (int n = 0; n < 4; ++n) {
      float4 fv;
      fv.x = acc[m][n][0]; fv.y = acc[m][n][1]; fv.z = acc[m][n][2]; fv.w = acc[m][n][3];
      *(float4*)(rowp + n * 16 + lg * 4) = fv;
    }
  }
}

// ---------------- causal flash attention (v12: 8 waves, q-tile 128, KVBLK 128) -----
// 512 blocks (32 bh x 16 q-tiles of 128 rows) x 512 thr. Wave (qq,kp): q-cols
// [qt*128+qq*32,+32) x kv-half [u*128+kp*64,+64). 2 blocks/CU (64KB LDS) = 16
// waves/CU, but units/CU drop 66 -> 17 ({c,15-c} pairing via (pass>>1)&1 flip):
// fixed per-unit costs (barrier convoy, vmcnt drain, stage issue) amortize 4x.
// Static-max softmax, in-register P (cvt_pk+permlane), per-ct QK->SM->PV to cap
// VGPR. V-LDS rows 256B -> swizzle key row&15 (stage source + read, rule 21).
// kp-partials additive (static max) -> one LDS combine at the end.
__launch_bounds__(512, 4)
__global__ void attn_kernel(const __bf16* __restrict__ Q, const __bf16* __restrict__ K,
                            const __bf16* __restrict__ Vt, __bf16* __restrict__ O) {
  __shared__ __bf16 Klds[2][128 * 64];   // [kv][hd] 128B rows, key kv&7
  __shared__ __bf16 Vlds[2][64 * 128];   // [hd][kv] 256B rows, key hd&15
  const int f = blockIdx.x;
  const int xcd = f & 7, g = f >> 3;     // 64 blocks per XCD = 4 bh x 16 q-tiles
  const int pass = g >> 4, g4 = g & 15;
  const int bh = xcd * 4 + pass;
  const int qt = ((pass >> 1) & 1) ? (15 - g4) : g4;  // CU pair {c,15-c} -> 17 units
  const int tid = threadIdx.x;
  const int lane = tid & 63, wid = tid >> 6;
  const int qq = wid >> 1, kp = wid & 1;       // wave's q-quarter / kv-half
  const int q31 = lane & 31, hh = lane >> 5;   // lane's q-col / split
  const int k3 = q31 & 7;                      // K row-XOR key (128B rows)
  const int v15 = q31 & 15;                    // V row-XOR key (256B rows)
  const __bf16* Qp = Q + (size_t)bh * Tc * HDc;
  const char* Kb = (const char*)(K + (size_t)bh * Tc * HDc);
  const char* Vb = (const char*)(Vt + (size_t)bh * HDc * Tc);

  const int units = qt + 1;

  // staging (8 waves cooperatively): K 2 instrs (64 rows each), V 2 instrs (32 rows)
  const int sr = tid >> 3;                               // K row within instr
  const int sxor = ((tid & 7) ^ (sr & 7)) << 4;          // K pre-swizzled src col
  const int vr = tid >> 4;                               // V row within instr
  const int vxor = ((tid & 15) ^ (vr & 15)) << 4;        // V pre-swizzled src col
  const char* vsrc = Vb + (size_t)vr * (Tc * 2) + vxor;

  const int q0w = qt * 128 + qq * 32;
  bf16x8s qf[4];
#pragma unroll
  for (int ks = 0; ks < 4; ++ks)
    qf[ks] = *(const bf16x8s*)(Qp + (q0w + q31) * HDc + ks * 16 + hh * 8);

  const int b = bh >> 4, h = bh & 15;

  f32x16 acc0 = {}, acc1 = {};
  float lsum = 0.f;

#define STAGE(IT, BUF)                                                                   \
  do {                                                                                   \
    _Pragma("unroll")                                                                    \
    for (int i_ = 0; i_ < 2; ++i_) {                                                     \
      __builtin_amdgcn_global_load_lds(                                                  \
          (gvoid_t*)(Kb + (size_t)((IT) * 128 + i_ * 64 + sr) * 128 + sxor),             \
          (lvoid_t*)((char*)Klds[BUF] + i_ * 8192 + wid * 1024), 16, 0, 0);              \
      __builtin_amdgcn_global_load_lds(                                                  \
          (gvoid_t*)(vsrc + (size_t)i_ * 32 * (Tc * 2) + (IT) * 256),                    \
          (lvoid_t*)((char*)Vlds[BUF] + i_ * 8192 + wid * 1024), 16, 0, 0);              \
    }                                                                                    \
  } while (0)

  STAGE(0, 0);
  asm volatile("s_waitcnt vmcnt(0)" ::: "memory");
  __builtin_amdgcn_sched_barrier(0);
  __builtin_amdgcn_s_barrier();
  __builtin_amdgcn_sched_barrier(0);

  for (int u = 0; u < units; ++u) {
    if (u + 1 < units) STAGE(u + 1, (u + 1) & 1);
    __builtin_amdgcn_sched_barrier(0);

    const bool last = (u == qt);
    if (!(last && kp == 1 && qq < 2)) {  // fully-masked waves skip (wave-uniform)
      const char* Kl = (const char*)Klds[u & 1];
      const char* Vl = (const char*)Vlds[u & 1];
      const bool fin = last && ((qq >> 1) == kp);   // partially-masked waves
      const int thr = q0w + q31 - u * 128 - kp * 64 - 4 * hh;  // mask: ct*32+n*8+j > thr

#pragma unroll
      for (int ct = 0; ct < 2; ++ct) {
        // ---- QK^T over 32 kv (swapped: D[kv][q], lane owns q-col) ----
        bf16x8s kf[4];
#pragma unroll
        for (int ks = 0; ks < 4; ++ks)
          kf[ks] = *(const bf16x8s*)(Kl + (kp * 64 + ct * 32 + q31) * 128 +
                                     (((2 * ks + hh) ^ k3) << 4));
        f32x16 z = {};
        __builtin_amdgcn_s_setprio(1);
#pragma unroll
        for (int ks = 0; ks < 4; ++ks)
          z = __builtin_amdgcn_mfma_f32_32x32x16_bf16(kf[ks], qf[ks], z, 0, 0, 0);
        __builtin_amdgcn_s_setprio(0);

        // ---- static-max softmax + pack ----
        unsigned w0[4], w1[4];
#pragma unroll
        for (int n = 0; n < 4; ++n) {
          float e[4];
#pragma unroll
          for (int j = 0; j < 4; ++j) {
            float ev = __builtin_amdgcn_exp2f(z[n * 4 + j]);
            if (fin && (ct * 32 + n * 8 + j > thr)) ev = 0.f;
            lsum += ev;
            e[j] = ev;
          }
          asm("v_cvt_pk_bf16_f32 %0, %1, %2" : "=v"(w0[n]) : "v"(e[0]), "v"(e[1]));
          asm("v_cvt_pk_bf16_f32 %0, %1, %2" : "=v"(w1[n]) : "v"(e[2]), "v"(e[3]));
        }

        // ---- assemble PV B-frags in registers (T12) ----
        bf16x8s pfr[2];
#pragma unroll
        for (int ks2 = 0; ks2 < 2; ++ks2) {
          unsigned a = w0[2 * ks2], bb2 = w0[2 * ks2 + 1];
          unsigned c = w1[2 * ks2], d = w1[2 * ks2 + 1];
          asm volatile("v_permlane32_swap_b32 %0, %1" : "+v"(a), "+v"(bb2));
          asm volatile("v_permlane32_swap_b32 %0, %1" : "+v"(c), "+v"(d));
          union { unsigned u[4]; bf16x8s v; } uu;
          uu.u[0] = a; uu.u[1] = c; uu.u[2] = bb2; uu.u[3] = d;
          pfr[ks2] = uu.v;
        }

        // ---- PV over these 32 kv: D[hd][q] ----
        __builtin_amdgcn_s_setprio(1);
#pragma unroll
        for (int ks2 = 0; ks2 < 2; ++ks2) {
          const int so = ((kp * 8 + ct * 4 + 2 * ks2 + hh) ^ v15) << 4;
          const bf16x8s va0 = *(const bf16x8s*)(Vl + q31 * 256 + so);
          const bf16x8s va1 = *(const bf16x8s*)(Vl + (32 + q31) * 256 + so);
          acc0 = __builtin_amdgcn_mfma_f32_32x32x16_bf16(va0, pfr[ks2], acc0, 0, 0, 0);
          acc1 = __builtin_amdgcn_mfma_f32_32x32x16_bf16(va1, pfr[ks2], acc1, 0, 0, 0);
        }
        __builtin_amdgcn_s_setprio(0);
      }
    }

    if (u + 1 < units) {
      asm volatile("s_waitcnt vmcnt(0)" ::: "memory");  // stage(u+1) landed
      __builtin_amdgcn_sched_barrier(0);
      __builtin_amdgcn_s_barrier();  // all waves done with buf[u&1]; buf[(u+1)&1] ready
      __builtin_amdgcn_sched_barrier(0);
    }
  }
#undef STAGE

  // ---- kp-pair combine (static max => additive), then finalize ----
  __syncthreads();  // all K/V reads done; buffers become scratch
  float* kscr = (float*)&Klds[0][0];   // 32KB: qq*2048 floats per pair
  float* lscr = (float*)&Vlds[0][0];
  if (kp == 1) {
#pragma unroll
    for (int i = 0; i < 16; ++i) {
      kscr[qq * 2048 + i * 64 + lane] = acc0[i];
      kscr[qq * 2048 + 1024 + i * 64 + lane] = acc1[i];
    }
    lscr[qq * 64 + lane] = lsum;
  }
  __syncthreads();
  if (kp == 0) {
#pragma unroll
    for (int i = 0; i < 16; ++i) {
      acc0[i] += kscr[qq * 2048 + i * 64 + lane];
      acc1[i] += kscr[qq * 2048 + 1024 + i * 64 + lane];
    }
    lsum += lscr[qq * 64 + lane];
    const float lt = lsum + __shfl_xor(lsum, 32);
    const float linv = 1.f / lt;
    const int t = q0w + q31;
    __bf16* dst = O + ((size_t)b * Tc + t) * Dc + h * HDc;
#pragma unroll
    for (int qd = 0; qd < 4; ++qd) {
      bf16x4 o0, o1;
#pragma unroll
      for (int j = 0; j < 4; ++j) {
        o0[j] = (__bf16)(acc0[qd * 4 + j] * linv);
        o1[j] = (__bf16)(acc1[qd * 4 + j] * linv);
      }
      *(bf16x4*)(dst + qd * 8 + hh * 4) = o0;
      *(bf16x4*)(dst + 32 + qd * 8 + hh * 4) = o1;
    }
  }
}

// ---------------- launch ----------------
extern "C" void kernel_launch(void* const* d_in, const int* in_sizes, int n_in,
                              void* d_out, int out_size, void* d_ws, size_t ws_size,
                              hipStream_t stream) {
  const float* x   = (const float*)d_in[0];
  const float* cbt = (const float*)d_in[1];
  const float* sbt = (const float*)d_in[2];
  const float* Wq  = (const float*)d_in[3];
  const float* Wk  = (const float*)d_in[4];
  const float* Wv  = (const float*)d_in[5];
  const float* Wp  = (const float*)d_in[6];
  float* out = (float*)d_out;
  char* ws = (char*)d_ws;
  __bf16* xb = (__bf16*)(ws);
  __bf16* wb = (__bf16*)(ws + (8u << 20));
  __bf16* qb = (__bf16*)(ws + (16u << 20));
  __bf16* vt = (__bf16*)(ws + (40u << 20));
  __bf16* ao = (__bf16*)(ws + (48u << 20));
  __bf16* kb = qb + (size_t)Mc * Dc;

  cvt_all<<<8192, 256, 0, stream>>>(x, Wq, Wk, Wv, Wp, xb, wb);
  gemm_qkv<<<dim3(8, 32, 3), 256, 0, stream>>>(xb, wb, qb, vt, cbt, sbt);
  attn_kernel<<<512, 512, 0, stream>>>(qb, kb, vt, ao);
  gemm_proj<<<dim3(16, 32), 256, 0, stream>>>(ao, wb + 3u * (Dc * Dc), out);
}